// Round 1
// baseline (369.593 us; speedup 1.0000x reference)
//
#include <hip/hip_runtime.h>

#define OBS_DIM 1024
#define ACT_DIM 8
#define HIDDEN  64
#define BATCH   131072
#define MTILE   64
#define KTILE   64
#define PAD     68            // 68*4B = 272B row stride: 16B-aligned, breaks pow2 bank pattern
#define NBLOCKS (BATCH / MTILE)

__device__ __forceinline__ float fast_tanh(float x) {
    // tanh(x) = 1 - 2/(exp(2x)+1); saturates correctly at +-1 for large |x|
    float e = __expf(2.0f * x);
    return 1.0f - 2.0f / (e + 1.0f);
}

__global__ __launch_bounds__(256) void actor_critic_fused(
    const float* __restrict__ obs,
    const float* __restrict__ w_in,
    const float* __restrict__ b_in,
    const float* __restrict__ w_h1,
    const float* __restrict__ b_h1,
    const float* __restrict__ w_pi,
    const float* __restrict__ b_pi,
    const float* __restrict__ w_v,
    const float* __restrict__ b_v,
    const float* __restrict__ log_std,
    float* __restrict__ out)
{
    __shared__ float sA[KTILE * PAD];    // obs^T tile [k][row]; later z^T [h][row]
    __shared__ float sB[KTILE * PAD];    // w_in^T tile [k][h]; later wdq^T [h][o]
    __shared__ float sX[HIDDEN * PAD];   // x^T [h][row]
    __shared__ float sH[9 * PAD];        // head weights [out][h] (w_pi rows 0..7, w_v row 8)

    const int tid = threadIdx.x;
    const int tc  = tid & 15;       // output-col tile (h)
    const int tr  = tid >> 4;       // row tile
    const int r0  = tr * 4;
    const int h0  = tc * 4;
    const int row0 = blockIdx.x * MTILE;

    // stage head weights once
    for (int t = tid; t < 9 * HIDDEN; t += 256) {
        int o = t >> 6, h = t & 63;
        sH[o * PAD + h] = (o < 8) ? w_pi[o * HIDDEN + h] : w_v[h];
    }

    float acc[4][4] = {{0.f}};

    // ---- layer 1: x = tanh(obs @ w_in^T + b_in), K = 1024 tiled by 64 ----
    for (int kt = 0; kt < OBS_DIM; kt += KTILE) {
        __syncthreads();   // previous tile's reads done before overwrite
        #pragma unroll
        for (int i = 0; i < 4; ++i) {
            const int row = tr + i * 16;   // 0..63 (row of obs tile, also h-row of w_in)
            const float4 ov = *(const float4*)&obs[(size_t)(row0 + row) * OBS_DIM + kt + tc * 4];
            sA[(tc*4+0)*PAD + row] = ov.x;
            sA[(tc*4+1)*PAD + row] = ov.y;
            sA[(tc*4+2)*PAD + row] = ov.z;
            sA[(tc*4+3)*PAD + row] = ov.w;
            const float4 wv = *(const float4*)&w_in[(size_t)row * OBS_DIM + kt + tc * 4];
            sB[(tc*4+0)*PAD + row] = wv.x;
            sB[(tc*4+1)*PAD + row] = wv.y;
            sB[(tc*4+2)*PAD + row] = wv.z;
            sB[(tc*4+3)*PAD + row] = wv.w;
        }
        __syncthreads();
        #pragma unroll 8
        for (int k = 0; k < KTILE; ++k) {
            const float4 a4 = *(const float4*)&sA[k * PAD + r0];
            const float4 b4 = *(const float4*)&sB[k * PAD + h0];
            const float av[4] = {a4.x, a4.y, a4.z, a4.w};
            const float bv[4] = {b4.x, b4.y, b4.z, b4.w};
            #pragma unroll
            for (int i = 0; i < 4; ++i)
                #pragma unroll
                for (int j = 0; j < 4; ++j)
                    acc[i][j] = fmaf(av[i], bv[j], acc[i][j]);
        }
    }

    // x = tanh(acc + b_in) -> sX[h][row] (transposed for layer-2 consumption)
    #pragma unroll
    for (int j = 0; j < 4; ++j) {
        const float b = b_in[h0 + j];
        float4 xv;
        xv.x = fast_tanh(acc[0][j] + b);
        xv.y = fast_tanh(acc[1][j] + b);
        xv.z = fast_tanh(acc[2][j] + b);
        xv.w = fast_tanh(acc[3][j] + b);
        *(float4*)&sX[(h0 + j) * PAD + r0] = xv;
    }
    __syncthreads();   // all layer-1 sB reads done; sX writes done

    // ---- in-block NVFP4 fake-quant dequant of w_h1 -> sB[h][o] (transposed) ----
    {
        const int o  = tid >> 2;   // 0..63 output row of w_h1
        const int hb = tid & 3;    // 16-elem block along input dim
        float v[16];
        #pragma unroll
        for (int i = 0; i < 4; ++i) {
            const float4 t4 = *(const float4*)&w_h1[o * HIDDEN + hb * 16 + i * 4];
            v[i*4+0] = t4.x; v[i*4+1] = t4.y; v[i*4+2] = t4.z; v[i*4+3] = t4.w;
        }
        float amax = 0.f;
        #pragma unroll
        for (int i = 0; i < 16; ++i) amax = fmaxf(amax, fabsf(v[i]));
        float scale = amax / 6.0f;
        if (scale == 0.f) scale = 1.f;
        #pragma unroll
        for (int i = 0; i < 16; ++i) {
            float xq = v[i] / scale;
            float ax = fabsf(xq);
            float q;
            if      (ax <= 0.25f) q = 0.0f;   // ties -> lower grid point (argmin first-index)
            else if (ax <= 0.75f) q = 0.5f;
            else if (ax <= 1.25f) q = 1.0f;
            else if (ax <= 1.75f) q = 1.5f;
            else if (ax <= 2.5f)  q = 2.0f;
            else if (ax <= 3.5f)  q = 3.0f;
            else if (ax <= 5.0f)  q = 4.0f;
            else                  q = 6.0f;
            q = (xq < 0.f) ? -q : q;
            sB[(hb * 16 + i) * PAD + o] = q * scale;
        }
    }
    __syncthreads();

    // ---- layer 2: z = tanh(x @ wdq^T + b_h1) ----
    float acc2[4][4] = {{0.f}};
    #pragma unroll 8
    for (int k = 0; k < HIDDEN; ++k) {
        const float4 a4 = *(const float4*)&sX[k * PAD + r0];
        const float4 b4 = *(const float4*)&sB[k * PAD + h0];
        const float av[4] = {a4.x, a4.y, a4.z, a4.w};
        const float bv[4] = {b4.x, b4.y, b4.z, b4.w};
        #pragma unroll
        for (int i = 0; i < 4; ++i)
            #pragma unroll
            for (int j = 0; j < 4; ++j)
                acc2[i][j] = fmaf(av[i], bv[j], acc2[i][j]);
    }
    // z -> sA[h][row] (reuse; sA reads finished in layer 1)
    #pragma unroll
    for (int j = 0; j < 4; ++j) {
        const float b = b_h1[h0 + j];
        float4 zv;
        zv.x = fast_tanh(acc2[0][j] + b);
        zv.y = fast_tanh(acc2[1][j] + b);
        zv.z = fast_tanh(acc2[2][j] + b);
        zv.w = fast_tanh(acc2[3][j] + b);
        *(float4*)&sA[(h0 + j) * PAD + r0] = zv;
    }
    __syncthreads();

    // ---- heads: mean (8) + value (1) per row, plus std broadcast ----
    for (int t = tid; t < MTILE * 9; t += 256) {
        const int r = t / 9;
        const int o = t - r * 9;
        float a3 = (o < 8) ? b_pi[o] : b_v[0];
        #pragma unroll 8
        for (int h = 0; h < HIDDEN; ++h)
            a3 = fmaf(sA[h * PAD + r], sH[o * PAD + h], a3);
        const size_t rg = (size_t)(row0 + r);
        if (o < 8) out[rg * 8 + o] = a3;
        else       out[(size_t)2 * BATCH * 8 + rg] = a3;
    }
    for (int t = tid; t < MTILE * 8; t += 256) {
        const int r = t >> 3, a = t & 7;
        out[(size_t)BATCH * 8 + (size_t)(row0 + r) * 8 + a] = __expf(log_std[a]);
    }
}

extern "C" void kernel_launch(void* const* d_in, const int* in_sizes, int n_in,
                              void* d_out, int out_size, void* d_ws, size_t ws_size,
                              hipStream_t stream) {
    (void)in_sizes; (void)n_in; (void)d_ws; (void)ws_size; (void)out_size;
    const float* obs   = (const float*)d_in[0];
    const float* w_in  = (const float*)d_in[1];
    const float* b_in  = (const float*)d_in[2];
    const float* w_h1  = (const float*)d_in[3];
    const float* b_h1  = (const float*)d_in[4];
    const float* w_pi  = (const float*)d_in[5];
    const float* b_pi  = (const float*)d_in[6];
    const float* w_v   = (const float*)d_in[7];
    const float* b_v   = (const float*)d_in[8];
    const float* lstd  = (const float*)d_in[9];
    float* out = (float*)d_out;

    hipLaunchKernelGGL(actor_critic_fused, dim3(NBLOCKS), dim3(256), 0, stream,
                       obs, w_in, b_in, w_h1, b_h1, w_pi, b_pi, w_v, b_v, lstd, out);
}

// Round 2
// 194.625 us; speedup vs baseline: 1.8990x; 1.8990x over previous
//
#include <hip/hip_runtime.h>
#include <hip/hip_bf16.h>

#define OBS_DIM 1024
#define ACT_DIM 8
#define HIDDEN  64
#define BATCH   131072
#define NBLOCKS (BATCH / 64)

typedef short bf16x8 __attribute__((ext_vector_type(8)));
typedef float f32x4  __attribute__((ext_vector_type(4)));

__device__ __forceinline__ ushort f2bf(float f) {
    union { __hip_bfloat16 h; ushort u; } c;
    c.h = __float2bfloat16(f);
    return c.u;
}

__device__ __forceinline__ float fast_tanh(float x) {
    float e = __expf(2.0f * x);
    return 1.0f - 2.0f / (e + 1.0f);
}

__device__ __forceinline__ bf16x8 pack8(float4 a, float4 b) {
    bf16x8 r;
    r[0] = (short)f2bf(a.x); r[1] = (short)f2bf(a.y);
    r[2] = (short)f2bf(a.z); r[3] = (short)f2bf(a.w);
    r[4] = (short)f2bf(b.x); r[5] = (short)f2bf(b.y);
    r[6] = (short)f2bf(b.z); r[7] = (short)f2bf(b.w);
    return r;
}

// tiny pre-kernel: w_in fp32 -> bf16 in workspace (65536 elems)
__global__ __launch_bounds__(256) void w_in_to_bf16(const float* __restrict__ w_in,
                                                    ushort* __restrict__ wbf) {
    const int i = (blockIdx.x * 256 + threadIdx.x) * 4;
    float4 v = *(const float4*)&w_in[i];
    ushort4 o;
    o.x = f2bf(v.x); o.y = f2bf(v.y); o.z = f2bf(v.z); o.w = f2bf(v.w);
    *(ushort4*)&wbf[i] = o;
}

template <bool USE_WS>
__global__ __launch_bounds__(256) void ac_mfma(
    const float* __restrict__ obs,  const float* __restrict__ w_in,
    const float* __restrict__ b_in, const float* __restrict__ w_h1,
    const float* __restrict__ b_h1, const float* __restrict__ w_pi,
    const float* __restrict__ b_pi, const float* __restrict__ w_v,
    const float* __restrict__ b_v,  const float* __restrict__ log_std,
    const ushort* __restrict__ wbf, float* __restrict__ out)
{
    __shared__ ushort x_lds[64][72];   // x^T? no: x[row][h], stride 144B (16B-aligned)
    __shared__ ushort z_lds[64][72];   // z[row][h]
    __shared__ ushort wdq[64][72];     // dequantized w_h1 [o][k] bf16
    __shared__ ushort wh[16][72];      // head weights [o][h]: 0-7 w_pi, 8 w_v, 9-15 zero

    const int tid = threadIdx.x;
    const int w   = tid >> 6;          // wave 0..3 -> 16-row strip
    const int l   = tid & 63;
    const int lr  = l & 15;            // MFMA row/col within fragment
    const int lg  = l >> 4;            // k-group (8 elems each)
    const int row0 = blockIdx.x * 64;

    // ---- NVFP4 fake-quant dequant of w_h1 -> LDS bf16 (one 16-block per thread) ----
    {
        const int o  = tid >> 2;
        const int hb = tid & 3;
        const float* wp = w_h1 + o * HIDDEN + hb * 16;
        float v[16];
        #pragma unroll
        for (int i = 0; i < 4; ++i) {
            float4 t4 = *(const float4*)(wp + i * 4);
            v[i*4+0] = t4.x; v[i*4+1] = t4.y; v[i*4+2] = t4.z; v[i*4+3] = t4.w;
        }
        float amax = 0.f;
        #pragma unroll
        for (int i = 0; i < 16; ++i) amax = fmaxf(amax, fabsf(v[i]));
        float scale = amax / 6.0f;
        if (scale == 0.f) scale = 1.f;
        #pragma unroll
        for (int i = 0; i < 16; ++i) {
            float xq = v[i] / scale;        // exact div to match ref bucket boundaries
            float ax = fabsf(xq);
            float q;
            if      (ax <= 0.25f) q = 0.0f;
            else if (ax <= 0.75f) q = 0.5f;
            else if (ax <= 1.25f) q = 1.0f;
            else if (ax <= 1.75f) q = 1.5f;
            else if (ax <= 2.5f)  q = 2.0f;
            else if (ax <= 3.5f)  q = 3.0f;
            else if (ax <= 5.0f)  q = 4.0f;
            else                  q = 6.0f;
            q = (xq < 0.f) ? -q : q;
            wdq[o][hb * 16 + i] = f2bf(q * scale);
        }
    }
    // ---- head weights -> LDS bf16 ----
    for (int t = tid; t < 16 * 64; t += 256) {
        const int o = t >> 6, h = t & 63;
        float val = (o < 8) ? w_pi[o * HIDDEN + h] : (o == 8 ? w_v[h] : 0.0f);
        wh[o][h] = f2bf(val);
    }

    // ---- layer 1: 16-row strip x 64 cols per wave, K=1024, no LDS, no barriers ----
    f32x4 acc[4];
    #pragma unroll
    for (int t = 0; t < 4; ++t) acc[t] = (f32x4){0.f, 0.f, 0.f, 0.f};

    const float* ap = obs + (size_t)(row0 + w * 16 + lr) * OBS_DIM + lg * 8;
    const int boff = lr * OBS_DIM + lg * 8;

    #pragma unroll 2
    for (int ks = 0; ks < OBS_DIM / 32; ++ks) {
        float4 a0 = *(const float4*)(ap + ks * 32);
        float4 a1 = *(const float4*)(ap + ks * 32 + 4);
        bf16x8 af = pack8(a0, a1);
        #pragma unroll
        for (int t = 0; t < 4; ++t) {
            bf16x8 bfr;
            if constexpr (USE_WS) {
                bfr = *(const bf16x8*)(wbf + t * 16 * OBS_DIM + boff + ks * 32);
            } else {
                const float* bp = w_in + t * 16 * OBS_DIM + boff + ks * 32;
                float4 b0 = *(const float4*)bp;
                float4 b1 = *(const float4*)(bp + 4);
                bfr = pack8(b0, b1);
            }
            acc[t] = __builtin_amdgcn_mfma_f32_16x16x32_bf16(af, bfr, acc[t], 0, 0, 0);
        }
    }

    // x = tanh(acc + b_in) -> x_lds[row][h]  (C layout: row=lg*4+r, col=lr per 16-tile)
    #pragma unroll
    for (int t = 0; t < 4; ++t) {
        const float b = b_in[t * 16 + lr];
        #pragma unroll
        for (int r = 0; r < 4; ++r)
            x_lds[w * 16 + lg * 4 + r][t * 16 + lr] = f2bf(fast_tanh(acc[t][r] + b));
    }
    __syncthreads();

    // ---- layer 2: z = tanh(x @ wdq^T + b_h1), K=64 -> 8 MFMAs/wave ----
    f32x4 acc2[4];
    #pragma unroll
    for (int t = 0; t < 4; ++t) acc2[t] = (f32x4){0.f, 0.f, 0.f, 0.f};
    #pragma unroll
    for (int ks = 0; ks < 2; ++ks) {
        bf16x8 af = *(const bf16x8*)&x_lds[w * 16 + lr][ks * 32 + lg * 8];
        #pragma unroll
        for (int t = 0; t < 4; ++t) {
            bf16x8 bfr = *(const bf16x8*)&wdq[t * 16 + lr][ks * 32 + lg * 8];
            acc2[t] = __builtin_amdgcn_mfma_f32_16x16x32_bf16(af, bfr, acc2[t], 0, 0, 0);
        }
    }
    #pragma unroll
    for (int t = 0; t < 4; ++t) {
        const float b = b_h1[t * 16 + lr];
        #pragma unroll
        for (int r = 0; r < 4; ++r)
            z_lds[w * 16 + lg * 4 + r][t * 16 + lr] = f2bf(fast_tanh(acc2[t][r] + b));
    }
    __syncthreads();

    // ---- heads as one 16-col MFMA tile (cols 0-7 mean, 8 value) ----
    f32x4 acc3 = (f32x4){0.f, 0.f, 0.f, 0.f};
    #pragma unroll
    for (int ks = 0; ks < 2; ++ks) {
        bf16x8 af  = *(const bf16x8*)&z_lds[w * 16 + lr][ks * 32 + lg * 8];
        bf16x8 bfr = *(const bf16x8*)&wh[lr][ks * 32 + lg * 8];
        acc3 = __builtin_amdgcn_mfma_f32_16x16x32_bf16(af, bfr, acc3, 0, 0, 0);
    }
    #pragma unroll
    for (int r = 0; r < 4; ++r) {
        const int row = row0 + w * 16 + lg * 4 + r;
        if (lr < 8)
            out[(size_t)row * 8 + lr] = acc3[r] + b_pi[lr];
        else if (lr == 8)
            out[(size_t)2 * BATCH * 8 + row] = acc3[r] + b_v[0];
    }

    // ---- std broadcast: 512 floats per block ----
    {
        const int idx = tid * 2;
        const int rl = idx >> 3, a = idx & 7;
        float2 s;
        s.x = __expf(log_std[a]);
        s.y = __expf(log_std[a + 1]);
        *(float2*)&out[(size_t)BATCH * 8 + (size_t)(row0 + rl) * 8 + a] = s;
    }
}

extern "C" void kernel_launch(void* const* d_in, const int* in_sizes, int n_in,
                              void* d_out, int out_size, void* d_ws, size_t ws_size,
                              hipStream_t stream) {
    (void)in_sizes; (void)n_in; (void)out_size;
    const float* obs   = (const float*)d_in[0];
    const float* w_in  = (const float*)d_in[1];
    const float* b_in  = (const float*)d_in[2];
    const float* w_h1  = (const float*)d_in[3];
    const float* b_h1  = (const float*)d_in[4];
    const float* w_pi  = (const float*)d_in[5];
    const float* b_pi  = (const float*)d_in[6];
    const float* w_v   = (const float*)d_in[7];
    const float* b_v   = (const float*)d_in[8];
    const float* lstd  = (const float*)d_in[9];
    float* out = (float*)d_out;

    const size_t wbf_bytes = (size_t)HIDDEN * OBS_DIM * sizeof(ushort);
    if (ws_size >= wbf_bytes) {
        ushort* wbf = (ushort*)d_ws;
        hipLaunchKernelGGL(w_in_to_bf16, dim3(HIDDEN * OBS_DIM / 1024), dim3(256), 0, stream,
                           w_in, wbf);
        hipLaunchKernelGGL((ac_mfma<true>), dim3(NBLOCKS), dim3(256), 0, stream,
                           obs, w_in, b_in, w_h1, b_h1, w_pi, b_pi, w_v, b_v, lstd,
                           wbf, out);
    } else {
        hipLaunchKernelGGL((ac_mfma<false>), dim3(NBLOCKS), dim3(256), 0, stream,
                           obs, w_in, b_in, w_h1, b_h1, w_pi, b_pi, w_v, b_v, lstd,
                           (const ushort*)nullptr, out);
    }
}

// Round 3
// 169.507 us; speedup vs baseline: 2.1804x; 1.1482x over previous
//
#include <hip/hip_runtime.h>
#include <hip/hip_bf16.h>

#define OBS_DIM 1024
#define ACT_DIM 8
#define HIDDEN  64
#define BATCH   131072
#define NBLOCKS (BATCH / 64)
#define KCHUNK  128                    // floats staged per chunk per row
#define NCHUNK  (OBS_DIM / KCHUNK)     // 8

typedef short bf16x8 __attribute__((ext_vector_type(8)));
typedef short bf16x4 __attribute__((ext_vector_type(4)));
typedef float f32x4  __attribute__((ext_vector_type(4)));

__device__ __forceinline__ ushort f2bf(float f) {
    union { __hip_bfloat16 h; ushort u; } c;
    c.h = __float2bfloat16(f);
    return c.u;
}

__device__ __forceinline__ float fast_tanh(float x) {
    float e = __expf(2.0f * x);
    return 1.0f - 2.0f / (e + 1.0f);
}

__device__ __forceinline__ bf16x8 pack8(float4 a, float4 b) {
    bf16x8 r;
    r[0] = (short)f2bf(a.x); r[1] = (short)f2bf(a.y);
    r[2] = (short)f2bf(a.z); r[3] = (short)f2bf(a.w);
    r[4] = (short)f2bf(b.x); r[5] = (short)f2bf(b.y);
    r[6] = (short)f2bf(b.z); r[7] = (short)f2bf(b.w);
    return r;
}

// tiny pre-kernel: w_in fp32 -> bf16 in workspace (65536 elems)
__global__ __launch_bounds__(256) void w_in_to_bf16(const float* __restrict__ w_in,
                                                    ushort* __restrict__ wbf) {
    const int i = (blockIdx.x * 256 + threadIdx.x) * 4;
    float4 v = *(const float4*)&w_in[i];
    ushort4 o;
    o.x = f2bf(v.x); o.y = f2bf(v.y); o.z = f2bf(v.z); o.w = f2bf(v.w);
    *(ushort4*)&wbf[i] = o;
}

// LDS map (ushort units), total 16384 ushorts = 32 KB:
//   phase 1: stage[2][64][128]  bf16 A-tiles, XOR-swizzled (16B-slot granularity)
//   phase 2 (overlaid, after layer-1 compute done):
//     x   @ 0      [64][72]
//     z   @ 4608   [64][72]
//     wdq @ 9216   [64][72]
//     wh  @ 13824  [16][72]
template <bool USE_WS>
__global__ __launch_bounds__(256) void ac_mfma(
    const float* __restrict__ obs,  const float* __restrict__ w_in,
    const float* __restrict__ b_in, const float* __restrict__ w_h1,
    const float* __restrict__ b_h1, const float* __restrict__ w_pi,
    const float* __restrict__ b_pi, const float* __restrict__ w_v,
    const float* __restrict__ b_v,  const float* __restrict__ log_std,
    const ushort* __restrict__ wbf, float* __restrict__ out)
{
    __shared__ __align__(16) ushort smem[16384];

    const int tid = threadIdx.x;
    const int w   = tid >> 6;
    const int l   = tid & 63;
    const int lr  = l & 15;
    const int lg  = l >> 4;
    const int row0 = blockIdx.x * 64;

    // staging map: 32 consecutive lanes cover one row's 512B chunk contiguously
    const int srow = tid >> 5;            // row within each 8-row group (== row&7)
    const int scol = (tid & 31) * 4;      // elem offset within 128-elem chunk
    const int sswz = srow << 3;           // XOR swizzle (16B-slot bits 3-5 in elems)

    const int arow = w * 16 + lr;         // MFMA A row this lane reads
    const int aswz = (arow & 7) << 3;

    float4 sv[8];

#define LOADC(kc)                                                                  \
    _Pragma("unroll")                                                              \
    for (int i = 0; i < 8; ++i) {                                                  \
        const int row = i * 8 + srow;                                              \
        sv[i] = *(const float4*)&obs[(size_t)(row0 + row) * OBS_DIM +              \
                                     (kc) * KCHUNK + scol];                        \
    }

#define STOREC(kc)                                                                 \
    _Pragma("unroll")                                                              \
    for (int i = 0; i < 8; ++i) {                                                  \
        const int row = i * 8 + srow;                                              \
        bf16x4 v4;                                                                 \
        v4[0] = (short)f2bf(sv[i].x); v4[1] = (short)f2bf(sv[i].y);                \
        v4[2] = (short)f2bf(sv[i].z); v4[3] = (short)f2bf(sv[i].w);                \
        *(bf16x4*)&smem[((kc) & 1) * 8192 + row * 128 + (scol ^ sswz)] = v4;       \
    }

#define COMPUTE(kc)                                                                \
    {                                                                              \
        const int bb = ((kc) & 1) * 8192 + arow * 128;                             \
        _Pragma("unroll")                                                          \
        for (int s = 0; s < 4; ++s) {                                              \
            bf16x8 af = *(const bf16x8*)&smem[bb + ((s * 32 + lg * 8) ^ aswz)];    \
            const int ks = (kc) * 4 + s;                                           \
            _Pragma("unroll")                                                      \
            for (int t = 0; t < 4; ++t) {                                          \
                bf16x8 bfr;                                                        \
                if constexpr (USE_WS) {                                            \
                    bfr = *(const bf16x8*)(wbf + (size_t)(t * 16 + lr) * OBS_DIM + \
                                           ks * 32 + lg * 8);                      \
                } else {                                                           \
                    const float* bp = w_in + (size_t)(t * 16 + lr) * OBS_DIM +     \
                                      ks * 32 + lg * 8;                            \
                    bfr = pack8(*(const float4*)bp, *(const float4*)(bp + 4));     \
                }                                                                  \
                acc[t] = __builtin_amdgcn_mfma_f32_16x16x32_bf16(af, bfr,          \
                                                                 acc[t], 0, 0, 0); \
            }                                                                      \
        }                                                                          \
    }

    f32x4 acc[4];
    #pragma unroll
    for (int t = 0; t < 4; ++t) acc[t] = (f32x4){0.f, 0.f, 0.f, 0.f};

    // ---- layer 1: double-buffered staged pipeline over K=1024 ----
    LOADC(0)
    STOREC(0)
    __syncthreads();
    for (int kc = 1; kc < NCHUNK; ++kc) {
        LOADC(kc)          // issue next chunk's 8 independent 16B loads early
        COMPUTE(kc - 1)    // MFMA from LDS buf (kc-1)&1 while loads fly
        STOREC(kc)         // vmcnt drain + cvt + swizzled ds_write to buf kc&1
        __syncthreads();
    }
    COMPUTE(NCHUNK - 1)
    __syncthreads();       // stage buffers dead beyond this point

    ushort* x_lds = smem;               // [64][72]
    ushort* z_lds = smem + 4608;        // [64][72]
    ushort* wdq   = smem + 9216;        // [64][72]
    ushort* wh    = smem + 13824;       // [16][72]

    // x = tanh(acc + b_in) -> x_lds[row][h]
    #pragma unroll
    for (int t = 0; t < 4; ++t) {
        const float b = b_in[t * 16 + lr];
        #pragma unroll
        for (int r = 0; r < 4; ++r)
            x_lds[(w * 16 + lg * 4 + r) * 72 + t * 16 + lr] = f2bf(fast_tanh(acc[t][r] + b));
    }

    // ---- NVFP4 fake-quant dequant of w_h1 -> wdq bf16 ----
    {
        const int o  = tid >> 2;
        const int hb = tid & 3;
        const float* wp = w_h1 + o * HIDDEN + hb * 16;
        float v[16];
        #pragma unroll
        for (int i = 0; i < 4; ++i) {
            float4 t4 = *(const float4*)(wp + i * 4);
            v[i*4+0] = t4.x; v[i*4+1] = t4.y; v[i*4+2] = t4.z; v[i*4+3] = t4.w;
        }
        float amax = 0.f;
        #pragma unroll
        for (int i = 0; i < 16; ++i) amax = fmaxf(amax, fabsf(v[i]));
        float scale = amax / 6.0f;
        if (scale == 0.f) scale = 1.f;
        #pragma unroll
        for (int i = 0; i < 16; ++i) {
            float xq = v[i] / scale;
            float ax = fabsf(xq);
            float q;
            if      (ax <= 0.25f) q = 0.0f;
            else if (ax <= 0.75f) q = 0.5f;
            else if (ax <= 1.25f) q = 1.0f;
            else if (ax <= 1.75f) q = 1.5f;
            else if (ax <= 2.5f)  q = 2.0f;
            else if (ax <= 3.5f)  q = 3.0f;
            else if (ax <= 5.0f)  q = 4.0f;
            else                  q = 6.0f;
            q = (xq < 0.f) ? -q : q;
            wdq[o * 72 + hb * 16 + i] = f2bf(q * scale);
        }
    }
    // head weights -> wh
    for (int t2 = tid; t2 < 16 * 64; t2 += 256) {
        const int o = t2 >> 6, h = t2 & 63;
        float val = (o < 8) ? w_pi[o * HIDDEN + h] : (o == 8 ? w_v[h] : 0.0f);
        wh[o * 72 + h] = f2bf(val);
    }
    __syncthreads();

    // ---- layer 2: z = tanh(x @ wdq^T + b_h1), K=64 ----
    f32x4 acc2[4];
    #pragma unroll
    for (int t = 0; t < 4; ++t) acc2[t] = (f32x4){0.f, 0.f, 0.f, 0.f};
    #pragma unroll
    for (int ks = 0; ks < 2; ++ks) {
        bf16x8 af = *(const bf16x8*)&x_lds[(w * 16 + lr) * 72 + ks * 32 + lg * 8];
        #pragma unroll
        for (int t = 0; t < 4; ++t) {
            bf16x8 bfr = *(const bf16x8*)&wdq[(t * 16 + lr) * 72 + ks * 32 + lg * 8];
            acc2[t] = __builtin_amdgcn_mfma_f32_16x16x32_bf16(af, bfr, acc2[t], 0, 0, 0);
        }
    }
    #pragma unroll
    for (int t = 0; t < 4; ++t) {
        const float b = b_h1[t * 16 + lr];
        #pragma unroll
        for (int r = 0; r < 4; ++r)
            z_lds[(w * 16 + lg * 4 + r) * 72 + t * 16 + lr] = f2bf(fast_tanh(acc2[t][r] + b));
    }
    __syncthreads();

    // ---- heads as one 16-col MFMA tile (cols 0-7 mean, 8 value) ----
    f32x4 acc3 = (f32x4){0.f, 0.f, 0.f, 0.f};
    #pragma unroll
    for (int ks = 0; ks < 2; ++ks) {
        bf16x8 af  = *(const bf16x8*)&z_lds[(w * 16 + lr) * 72 + ks * 32 + lg * 8];
        bf16x8 bfr = *(const bf16x8*)&wh[lr * 72 + ks * 32 + lg * 8];
        acc3 = __builtin_amdgcn_mfma_f32_16x16x32_bf16(af, bfr, acc3, 0, 0, 0);
    }
    #pragma unroll
    for (int r = 0; r < 4; ++r) {
        const int row = row0 + w * 16 + lg * 4 + r;
        if (lr < 8)
            out[(size_t)row * 8 + lr] = acc3[r] + b_pi[lr];
        else if (lr == 8)
            out[(size_t)2 * BATCH * 8 + row] = acc3[r] + b_v[0];
    }

    // ---- std broadcast ----
    {
        const int idx = tid * 2;
        const int rl = idx >> 3, a = idx & 7;
        float2 s;
        s.x = __expf(log_std[a]);
        s.y = __expf(log_std[a + 1]);
        *(float2*)&out[(size_t)BATCH * 8 + (size_t)(row0 + rl) * 8 + a] = s;
    }
#undef LOADC
#undef STOREC
#undef COMPUTE
}

extern "C" void kernel_launch(void* const* d_in, const int* in_sizes, int n_in,
                              void* d_out, int out_size, void* d_ws, size_t ws_size,
                              hipStream_t stream) {
    (void)in_sizes; (void)n_in; (void)out_size;
    const float* obs   = (const float*)d_in[0];
    const float* w_in  = (const float*)d_in[1];
    const float* b_in  = (const float*)d_in[2];
    const float* w_h1  = (const float*)d_in[3];
    const float* b_h1  = (const float*)d_in[4];
    const float* w_pi  = (const float*)d_in[5];
    const float* b_pi  = (const float*)d_in[6];
    const float* w_v   = (const float*)d_in[7];
    const float* b_v   = (const float*)d_in[8];
    const float* lstd  = (const float*)d_in[9];
    float* out = (float*)d_out;

    const size_t wbf_bytes = (size_t)HIDDEN * OBS_DIM * sizeof(ushort);
    if (ws_size >= wbf_bytes) {
        ushort* wbf = (ushort*)d_ws;
        hipLaunchKernelGGL(w_in_to_bf16, dim3(HIDDEN * OBS_DIM / 1024), dim3(256), 0, stream,
                           w_in, wbf);
        hipLaunchKernelGGL((ac_mfma<true>), dim3(NBLOCKS), dim3(256), 0, stream,
                           obs, w_in, b_in, w_h1, b_h1, w_pi, b_pi, w_v, b_v, lstd,
                           wbf, out);
    } else {
        hipLaunchKernelGGL((ac_mfma<false>), dim3(NBLOCKS), dim3(256), 0, stream,
                           obs, w_in, b_in, w_h1, b_h1, w_pi, b_pi, w_v, b_v, lstd,
                           (const ushort*)nullptr, out);
    }
}